// Round 6
// baseline (763.384 us; speedup 1.0000x reference)
//
#include <hip/hip_runtime.h>

#define BB 256
#define HH 1024
#define MM 256
#define HS 128
#define NH 129  // HS+1

typedef __attribute__((ext_vector_type(8))) short short8;
typedef __attribute__((ext_vector_type(4))) float float4v;

__device__ __forceinline__ float sigmoidf_(float x) { return 1.0f / (1.0f + expf(-x)); }
__device__ __forceinline__ float gumbelf_(float u) { return -logf(1e-20f - logf(1e-20f + u)); }

__device__ __forceinline__ unsigned short f2bf(float x) {
    union { float f; unsigned u; } c; c.f = x;
    unsigned u = c.u;
    return (unsigned short)((u + 0x7FFFu + ((u >> 16) & 1u)) >> 16);
}

// ---------------------------------------------------------------- shared GEMM unit
// C(128x128) = A(128x512) * B(128x512)^T in bf16 MFMA 16x16x32; writes fp32 to pout.
__device__ __forceinline__ void gemm_unit(const unsigned short* __restrict__ Ap,
                                          const unsigned short* __restrict__ Bp,
                                          int bstr, int m0, int ncol0,
                                          float* __restrict__ pout,
                                          unsigned short* As, unsigned short* Bs) {
    int tid = threadIdx.x;
    int wave = tid >> 6, lane = tid & 63;
    int wm = wave >> 1, wn = wave & 1;
    int q = lane >> 4, lm = lane & 15;

    float4v acc[4][4];
    for (int i = 0; i < 4; ++i)
        for (int j = 0; j < 4; ++j)
            acc[i][j] = (float4v){0.f, 0.f, 0.f, 0.f};

    for (int kt = 0; kt < 512; kt += 64) {
        for (int rr = 0; rr < 4; ++rr) {
            int e = rr * 256 + tid;
            int row = e >> 3, cg = e & 7;
            *(uint4*)&As[row * 72 + cg * 8] =
                *(const uint4*)(Ap + (size_t)(m0 + row) * 3072 + kt + cg * 8);
            *(uint4*)&Bs[row * 72 + cg * 8] =
                *(const uint4*)(Bp + (size_t)row * bstr + kt + cg * 8);
        }
        __syncthreads();
        for (int ks = 0; ks < 64; ks += 32) {
            short8 av[4], bv[4];
            for (int i = 0; i < 4; ++i)
                av[i] = *(const short8*)&As[(wm * 64 + i * 16 + lm) * 72 + ks + q * 8];
            for (int j = 0; j < 4; ++j)
                bv[j] = *(const short8*)&Bs[(wn * 64 + j * 16 + lm) * 72 + ks + q * 8];
            for (int i = 0; i < 4; ++i)
                for (int j = 0; j < 4; ++j)
                    acc[i][j] = __builtin_amdgcn_mfma_f32_16x16x32_bf16(av[i], bv[j], acc[i][j], 0, 0, 0);
        }
        __syncthreads();
    }

    for (int i = 0; i < 4; ++i)
        for (int j = 0; j < 4; ++j) {
            int n = ncol0 + wn * 64 + j * 16 + lm;
            for (int reg = 0; reg < 4; ++reg) {
                int m = m0 + wm * 64 + i * 16 + q * 4 + reg;
                pout[(size_t)m * 3072 + n] = acc[i][j][reg];
            }
        }
}

// ---------------------------------------------------------------- L1: score1 (bx<256) + weight cvt (bx>=256)
__global__ __launch_bounds__(256) void k_phase1(const float* __restrict__ input_,
                                                const float* __restrict__ h0,
                                                const float* __restrict__ W_im,
                                                const float* __restrict__ W_hm,
                                                const float* __restrict__ fc1_w,
                                                const float* __restrict__ fc1_b,
                                                const float* __restrict__ mem,
                                                const float* __restrict__ last_usage,
                                                const float* __restrict__ u1,
                                                const float* __restrict__ W_ih,
                                                const float* __restrict__ W_hh,
                                                const float* __restrict__ W_rh,
                                                const float* __restrict__ W_s1,
                                                const float* __restrict__ W_s2,
                                                const float* __restrict__ W_s3,
                                                unsigned short* __restrict__ Abf,
                                                unsigned short* __restrict__ WtG,
                                                unsigned short* __restrict__ WtS,
                                                float* __restrict__ sg_out) {
    __shared__ __align__(16) unsigned char smem[14400];
    int bx = blockIdx.x, t = threadIdx.x;
    if (bx >= 256) {
        // ---- weight convert/transpose tile
        unsigned short (*T)[66] = (unsigned short (*)[66])smem;
        int tile = bx - 256;
        const float* src;
        unsigned short* dst;
        int k0, n0, sstr, dstr, krel;
        if (tile < 2304) {
            int kt = tile / 48, nt = tile % 48;
            k0 = kt * 64; n0 = nt * 64;
            src = (k0 < 1024) ? W_ih : (k0 < 2048) ? W_hh : W_rh;
            krel = k0 & 1023;
            dst = WtG; sstr = 3072; dstr = 3072;
        } else {
            int r = tile - 2304;
            int seg = r >> 8;
            int rem = r & 255;
            int kt = rem >> 4, nt = rem & 15;
            k0 = kt * 64; n0 = nt * 64;
            src = (seg == 0) ? W_s1 : (seg == 1) ? W_s2 : W_s3;
            krel = k0;
            dst = WtS + (size_t)seg * 1048576; sstr = 1024; dstr = 1024;
        }
        for (int i = 0; i < 4; ++i) {
            int e = i * 256 + t;
            int kk = e >> 4, nn0 = (e & 15) * 4;
            float4 v = *(const float4*)(src + (size_t)(krel + kk) * sstr + n0 + nn0);
            T[nn0 + 0][kk] = f2bf(v.x);
            T[nn0 + 1][kk] = f2bf(v.y);
            T[nn0 + 2][kk] = f2bf(v.z);
            T[nn0 + 3][kk] = f2bf(v.w);
        }
        __syncthreads();
        for (int i = 0; i < 8; ++i) {
            int e = i * 256 + t;
            int nn = e >> 5, kk2 = (e & 31) * 2;
            unsigned val = (unsigned)T[nn][kk2] | ((unsigned)T[nn][kk2 + 1] << 16);
            *(unsigned*)(dst + (size_t)(n0 + nn) * dstr + k0 + kk2) = val;
        }
        return;
    }
    // ---- score pass 1
    float* sx = (float*)smem;              // 1024
    float* sh = sx + 1024;                 // 1024
    float* sv = sh + 1024;                 // 1024
    float* red = sv + 1024;                // 256
    float* red2 = red + 256;               // 2
    float* sj = red2 + 2;                  // 129
    float* scb = sj + 129;                 // 1
    int b = bx;
    {
        float4 vx = *(const float4*)(input_ + (size_t)b * HH + t * 4);
        *(float4*)(sx + t * 4) = vx;
        ushort4 o; o.x = f2bf(vx.x); o.y = f2bf(vx.y); o.z = f2bf(vx.z); o.w = f2bf(vx.w);
        *(ushort4*)(Abf + (size_t)b * 3072 + t * 4) = o;
        float4 vh = *(const float4*)(h0 + (size_t)b * HH + t * 4);
        *(float4*)(sh + t * 4) = vh;
        ushort4 p; p.x = f2bf(vh.x); p.y = f2bf(vh.y); p.z = f2bf(vh.z); p.w = f2bf(vh.w);
        *(ushort4*)(Abf + (size_t)b * 3072 + 1024 + t * 4) = p;
    }
    __syncthreads();
    {   // read_head GEMV: j = t&127, 2-way K-split
        int j = t & 127, ks = t >> 7;
        int hb = ks * 512;
        float p = 0.f;
#pragma unroll 8
        for (int h = hb; h < hb + 512; ++h)
            p += sx[h] * W_im[h * NH + j] + sh[h] * W_hm[h * NH + j];
        red[ks * 128 + j] = p;
        if (t >= 254) {  // j = 128 handled by threads 254,255
            int k2 = t - 254;
            int hb2 = k2 * 512;
            float q = 0.f;
#pragma unroll 8
            for (int h = hb2; h < hb2 + 512; ++h)
                q += sx[h] * W_im[h * NH + 128] + sh[h] * W_hm[h * NH + 128];
            red2[k2] = q;
        }
    }
    __syncthreads();
    if (t < 128) sj[t] = tanhf(red[t] + red[128 + t]);
    else if (t == 128) sj[128] = tanhf(red2[0] + red2[1]);
    __syncthreads();
    {   // v projection: 4 cols per thread
        float a0 = 0.f, a1 = 0.f, a2 = 0.f, a3 = 0.f;
#pragma unroll 4
        for (int j = 0; j < HS; ++j) {
            float s = sj[j];
            const float* w = fc1_w + (size_t)j * HH + t;
            a0 += s * w[0]; a1 += s * w[256]; a2 += s * w[512]; a3 += s * w[768];
        }
        sv[t] = a0; sv[t + 256] = a1; sv[t + 512] = a2; sv[t + 768] = a3;
    }
    if (t < 64) {
        float p = sj[t] * fc1_b[t] + sj[t + 64] * fc1_b[t + 64];
        for (int off = 32; off > 0; off >>= 1) p += __shfl_down(p, off, 64);
        if (t == 0) *scb = p;
    }
    __syncthreads();
    float cb = *scb, hf = sj[128];
    int wave = t >> 6, lane = t & 63;
    float4 rv[4];
#pragma unroll
    for (int it = 0; it < 4; ++it) rv[it] = *(const float4*)(sv + it * 256 + lane * 4);
    for (int i = 0; i < 64; ++i) {
        int m = wave * 64 + i;
        const float* row = (m == 0) ? (h0 + (size_t)b * HH) : (mem + ((size_t)(b * MM + m)) * HH);
        float p = 0.f;
#pragma unroll
        for (int it = 0; it < 4; ++it) {
            float4 mv = *(const float4*)(row + it * 256 + lane * 4);
            p += mv.x * rv[it].x + mv.y * rv[it].y + mv.z * rv[it].z + mv.w * rv[it].w;
        }
        for (int off = 32; off > 0; off >>= 1) p += __shfl_down(p, off, 64);
        if (lane == 0) {
            float lu = sigmoidf_(last_usage[b * MM + m]);
            sg_out[b * MM + m] = p + cb + hf * lu + gumbelf_(u1[b * MM + m]);
        }
    }
}

// ---------------------------------------------------------------- L2: sel_score2 (bx<256) + gemm part1 (bx>=256)
__global__ __launch_bounds__(256) void k_phase2(const float* __restrict__ sg1,
                                                const float* __restrict__ mem,
                                                const float* __restrict__ h0,
                                                const float* __restrict__ input_,
                                                const float* __restrict__ W_im1,
                                                const float* __restrict__ W_hm1,
                                                const float* __restrict__ W_mm1,
                                                const float* __restrict__ bias_m1,
                                                const float* __restrict__ fc1_w,
                                                const float* __restrict__ fc1_b,
                                                const float* __restrict__ last_usage,
                                                const float* __restrict__ u2,
                                                unsigned short* __restrict__ Abf,
                                                const unsigned short* __restrict__ WtG,
                                                const unsigned short* __restrict__ WtS,
                                                float* __restrict__ wbp,
                                                float* __restrict__ Sp,
                                                float* __restrict__ sg_out) {
    __shared__ __align__(16) unsigned char smem[36864];
    int bx = blockIdx.x, t = threadIdx.x;
    if (bx >= 256) {
        // ---- GEMM part 1: units independent of entry
        unsigned short* As = (unsigned short*)smem;
        unsigned short* Bs = As + 128 * 72;
        int inst = bx - 256;
        int mtile = inst & 1, u = inst >> 1;   // u in [0,128)
        int m0 = mtile * 128;
        const unsigned short* Ap;
        const unsigned short* Bp;
        float* pout;
        int bstr, ncol0;
        if (u < 96) {
            int nt = u % 24, kidx = u / 24;    // kidx 0..3
            int ksel = kidx >> 1, khalf = kidx & 1;
            ncol0 = nt * 128;
            Bp = WtG + (size_t)ncol0 * 3072 + ksel * 1024 + khalf * 512;
            bstr = 3072;
            Ap = Abf + ksel * 1024 + khalf * 512;
            pout = wbp + (size_t)kidx * 786432;
        } else {
            int su = u - 96;
            int seg = su >> 4, rem = su & 15;
            int khalf = rem >> 3, nts = rem & 7;
            ncol0 = seg * 1024 + nts * 128;
            Bp = WtS + (size_t)seg * 1048576 + (size_t)(nts * 128) * 1024 + khalf * 512;
            bstr = 1024;
            Ap = Abf + seg * 1024 + khalf * 512;
            pout = Sp + (size_t)khalf * 786432;
        }
        gemm_unit(Ap, Bp, bstr, m0, ncol0, pout, As, Bs);
        return;
    }
    // ---- sel1 + head1 + scores pass 2
    float* sx = (float*)smem;              // 1024
    float* sh = sx + 1024;
    float* se = sh + 1024;
    float* sv = se + 1024;
    float* svals = sv + 1024;              // 256
    int* sidx = (int*)(svals + 256);       // 256
    float* red = (float*)(sidx + 256);     // 256
    float* red2 = red + 256;               // 2
    float* sj = red2 + 2;                  // 129
    float* scb = sj + 129;                 // 1
    int b = bx;
    svals[t] = sg1[b * MM + t];
    sidx[t] = t;
    __syncthreads();
    for (int s = 128; s > 0; s >>= 1) {
        if (t < s) {
            if (svals[t + s] > svals[t]) { svals[t] = svals[t + s]; sidx[t] = sidx[t + s]; }
        }
        __syncthreads();
    }
    int mstar = sidx[0];
    const float* erow = (mstar == 0) ? (h0 + (size_t)b * HH) : (mem + ((size_t)(b * MM + mstar)) * HH);
    {
        float4 e = *(const float4*)(erow + t * 4);
        *(float4*)(se + t * 4) = e;
        ushort4 o; o.x = f2bf(e.x); o.y = f2bf(e.y); o.z = f2bf(e.z); o.w = f2bf(e.w);
        *(ushort4*)(Abf + (size_t)b * 3072 + 2048 + t * 4) = o;
        *(float4*)(sx + t * 4) = *(const float4*)(input_ + (size_t)b * HH + t * 4);
        *(float4*)(sh + t * 4) = *(const float4*)(h0 + (size_t)b * HH + t * 4);
    }
    __syncthreads();
    {
        int j = t & 127, ks = t >> 7;
        int hb = ks * 512;
        float p = 0.f;
#pragma unroll 4
        for (int h = hb; h < hb + 512; ++h)
            p += sx[h] * W_im1[h * NH + j] + sh[h] * W_hm1[h * NH + j] + se[h] * W_mm1[h * NH + j];
        red[ks * 128 + j] = p;
        if (t >= 254) {
            int k2 = t - 254;
            int hb2 = k2 * 512;
            float q = 0.f;
#pragma unroll 4
            for (int h = hb2; h < hb2 + 512; ++h)
                q += sx[h] * W_im1[h * NH + 128] + sh[h] * W_hm1[h * NH + 128] + se[h] * W_mm1[h * NH + 128];
            red2[k2] = q;
        }
    }
    __syncthreads();
    if (t < 128) sj[t] = tanhf(bias_m1[t] + red[t] + red[128 + t]);
    else if (t == 128) sj[128] = tanhf(bias_m1[128] + red2[0] + red2[1]);
    __syncthreads();
    {
        float a0 = 0.f, a1 = 0.f, a2 = 0.f, a3 = 0.f;
#pragma unroll 4
        for (int j = 0; j < HS; ++j) {
            float s = sj[j];
            const float* w = fc1_w + (size_t)j * HH + t;
            a0 += s * w[0]; a1 += s * w[256]; a2 += s * w[512]; a3 += s * w[768];
        }
        sv[t] = a0; sv[t + 256] = a1; sv[t + 512] = a2; sv[t + 768] = a3;
    }
    if (t < 64) {
        float p = sj[t] * fc1_b[t] + sj[t + 64] * fc1_b[t + 64];
        for (int off = 32; off > 0; off >>= 1) p += __shfl_down(p, off, 64);
        if (t == 0) *scb = p;
    }
    __syncthreads();
    float cb = *scb, hf = sj[128];
    int wave = t >> 6, lane = t & 63;
    float4 rv[4];
#pragma unroll
    for (int it = 0; it < 4; ++it) rv[it] = *(const float4*)(sv + it * 256 + lane * 4);
    for (int i = 0; i < 64; ++i) {
        int m = wave * 64 + i;
        const float* row = (m == 0) ? (h0 + (size_t)b * HH) : (mem + ((size_t)(b * MM + m)) * HH);
        float p = 0.f;
#pragma unroll
        for (int it = 0; it < 4; ++it) {
            float4 mv = *(const float4*)(row + it * 256 + lane * 4);
            p += mv.x * rv[it].x + mv.y * rv[it].y + mv.z * rv[it].z + mv.w * rv[it].w;
        }
        for (int off = 32; off > 0; off >>= 1) p += __shfl_down(p, off, 64);
        if (lane == 0) {
            float lu = sigmoidf_(last_usage[b * MM + m]);
            sg_out[b * MM + m] = p + cb + hf * lu + gumbelf_(u2[b * MM + m]);
        }
    }
}

// ---------------------------------------------------------------- L3: gemm part2 (entry-dependent units)
__global__ __launch_bounds__(256) void k_gemm2(const unsigned short* __restrict__ Abf,
                                               const unsigned short* __restrict__ WtG,
                                               const unsigned short* __restrict__ WtS,
                                               float* __restrict__ wbp,
                                               float* __restrict__ Sp) {
    __shared__ unsigned short As[128 * 72];
    __shared__ unsigned short Bs[128 * 72];
    int bx = blockIdx.x;
    int mtile = bx & 1, u = bx >> 1;           // u in [0,64)
    int m0 = mtile * 128;
    const unsigned short* Ap;
    const unsigned short* Bp;
    float* pout;
    int bstr, ncol0;
    if (u < 48) {
        int nt = u % 24, khalf = u / 24;
        int kidx = 4 + khalf;                  // ksel = 2
        ncol0 = nt * 128;
        Bp = WtG + (size_t)ncol0 * 3072 + 2048 + khalf * 512;
        bstr = 3072;
        Ap = Abf + 2048 + khalf * 512;
        pout = wbp + (size_t)kidx * 786432;
    } else {
        int su = u - 48;
        int khalf = su >> 3, nts = su & 7;
        ncol0 = 2048 + nts * 128;
        Bp = WtS + (size_t)2 * 1048576 + (size_t)(nts * 128) * 1024 + khalf * 512;
        bstr = 1024;
        Ap = Abf + 2048 + khalf * 512;
        pout = Sp + (size_t)khalf * 786432;
    }
    gemm_unit(Ap, Bp, bstr, m0, ncol0, pout, As, Bs);
}

// ---------------------------------------------------------------- L4: final (fused sel2 + GRU epilogue)
__global__ __launch_bounds__(256) void k_final(const float* __restrict__ sg2,
                                               const float* __restrict__ mem,
                                               const float* __restrict__ wbp,
                                               const float* __restrict__ Sp,
                                               const float* __restrict__ h0,
                                               const float* __restrict__ bias,
                                               const float* __restrict__ b1,
                                               const float* __restrict__ b2,
                                               const float* __restrict__ b3,
                                               float* __restrict__ out) {
    __shared__ float svals[256];
    __shared__ int sidx[256];
    int b = blockIdx.x, t = threadIdx.x;
    svals[t] = sg2[b * MM + t];
    sidx[t] = t;
    __syncthreads();
    for (int s = 128; s > 0; s >>= 1) {
        if (t < s) {
            if (svals[t + s] > svals[t]) { svals[t] = svals[t + s]; sidx[t] = sidx[t + s]; }
        }
        __syncthreads();
    }
    int mstar = sidx[0];
    const float* erow = (mstar == 0) ? (h0 + (size_t)b * HH) : (mem + ((size_t)(b * MM + mstar)) * HH);
    float* o_row = out + (size_t)BB * HH + (size_t)b * 2 * HH;
    {
        int hb = t * 4;
        *(float4*)(o_row + HH + hb) = *(const float4*)(erow + hb);
    }
    int h = t * 4;
    size_t base = (size_t)b * 3072;
    float4 wsum[3];
#pragma unroll
    for (int g = 0; g < 3; ++g) {
        float4 a = make_float4(0.f, 0.f, 0.f, 0.f);
#pragma unroll
        for (int p = 0; p < 6; ++p) {
            float4 w = *(const float4*)(wbp + (size_t)p * 786432 + base + g * 1024 + h);
            a.x += w.x; a.y += w.y; a.z += w.z; a.w += w.w;
        }
        wsum[g] = a;
    }
    float4 bi0 = *(const float4*)(bias + h);
    float4 bi1 = *(const float4*)(bias + 1024 + h);
    float4 bi2 = *(const float4*)(bias + 2048 + h);
    float4 r4 = make_float4(sigmoidf_(wsum[0].x + bi0.x), sigmoidf_(wsum[0].y + bi0.y),
                            sigmoidf_(wsum[0].z + bi0.z), sigmoidf_(wsum[0].w + bi0.w));
    float4 z4 = make_float4(sigmoidf_(wsum[1].x + bi1.x), sigmoidf_(wsum[1].y + bi1.y),
                            sigmoidf_(wsum[1].z + bi1.z), sigmoidf_(wsum[1].w + bi1.w));
    float4 n4 = make_float4(sigmoidf_(wsum[2].x + bi2.x), sigmoidf_(wsum[2].y + bi2.y),
                            sigmoidf_(wsum[2].z + bi2.z), sigmoidf_(wsum[2].w + bi2.w));
    float4 s1, s2, s3;
    {
        float4 a0 = *(const float4*)(Sp + base + h);
        float4 a1 = *(const float4*)(Sp + 786432 + base + h);
        s1 = make_float4(a0.x + a1.x, a0.y + a1.y, a0.z + a1.z, a0.w + a1.w);
        a0 = *(const float4*)(Sp + base + 1024 + h);
        a1 = *(const float4*)(Sp + 786432 + base + 1024 + h);
        s2 = make_float4(a0.x + a1.x, a0.y + a1.y, a0.z + a1.z, a0.w + a1.w);
        a0 = *(const float4*)(Sp + base + 2048 + h);
        a1 = *(const float4*)(Sp + 786432 + base + 2048 + h);
        s3 = make_float4(a0.x + a1.x, a0.y + a1.y, a0.z + a1.z, a0.w + a1.w);
    }
    float4 v1 = *(const float4*)(b1 + h);
    float4 v2 = *(const float4*)(b2 + h);
    float4 v3 = *(const float4*)(b3 + h);
    float4 h0v = *(const float4*)(h0 + (size_t)b * HH + h);
    float4 hn, h1;
    hn.x = tanhf(s1.x + v1.x + r4.x * (s2.x + v2.x) + z4.x * (s3.x + v3.x));
    hn.y = tanhf(s1.y + v1.y + r4.y * (s2.y + v2.y) + z4.y * (s3.y + v3.y));
    hn.z = tanhf(s1.z + v1.z + r4.z * (s2.z + v2.z) + z4.z * (s3.z + v3.z));
    hn.w = tanhf(s1.w + v1.w + r4.w * (s2.w + v2.w) + z4.w * (s3.w + v3.w));
    h1.x = n4.x * hn.x + (1.f - n4.x) * h0v.x;
    h1.y = n4.y * hn.y + (1.f - n4.y) * h0v.y;
    h1.z = n4.z * hn.z + (1.f - n4.z) * h0v.z;
    h1.w = n4.w * hn.w + (1.f - n4.w) * h0v.w;
    *(float4*)(out + (size_t)b * HH + h) = h1;
    *(float4*)(o_row + h) = h1;
}

extern "C" void kernel_launch(void* const* d_in, const int* in_sizes, int n_in,
                              void* d_out, int out_size, void* d_ws, size_t ws_size,
                              hipStream_t stream) {
    const float* input_ = (const float*)d_in[0];
    const float* h0 = (const float*)d_in[1];
    const float* mem = (const float*)d_in[2];
    const float* last_usage = (const float*)d_in[3];
    const float* u1 = (const float*)d_in[4];
    const float* u2 = (const float*)d_in[5];
    const float* W_ih = (const float*)d_in[6];
    const float* W_hh = (const float*)d_in[7];
    const float* W_rh = (const float*)d_in[8];
    const float* W_s1 = (const float*)d_in[9];
    const float* W_s2 = (const float*)d_in[10];
    const float* W_s3 = (const float*)d_in[11];
    const float* bias = (const float*)d_in[12];
    const float* W_im = (const float*)d_in[13];
    const float* W_hm = (const float*)d_in[14];
    const float* fc1_w = (const float*)d_in[15];
    const float* fc1_b = (const float*)d_in[16];
    const float* W_im1 = (const float*)d_in[17];
    const float* W_hm1 = (const float*)d_in[18];
    const float* W_mm1 = (const float*)d_in[19];
    const float* bias_m1 = (const float*)d_in[20];
    const float* bias_1 = (const float*)d_in[21];
    const float* bias_2 = (const float*)d_in[22];
    const float* bias_3 = (const float*)d_in[23];
    float* out = (float*)d_out;

    float* ws = (float*)d_ws;
    float* sg1 = ws;                        // 65536
    float* sg2 = sg1 + 65536;               // 65536
    float* wbp = sg2 + 65536;               // 6 * 786432
    float* Sp = wbp + 6 * 786432;           // 2 * 786432
    unsigned short* Abf = (unsigned short*)(Sp + 2 * 786432);  // 786432 bf16
    unsigned short* WtG = Abf + 786432;     // 9437184 bf16
    unsigned short* WtS = WtG + 9437184;    // 3145728 bf16

    k_phase1<<<256 + 3072, 256, 0, stream>>>(input_, h0, W_im, W_hm, fc1_w, fc1_b,
                                             mem, last_usage, u1,
                                             W_ih, W_hh, W_rh, W_s1, W_s2, W_s3,
                                             Abf, WtG, WtS, sg1);
    k_phase2<<<512, 256, 0, stream>>>(sg1, mem, h0, input_, W_im1, W_hm1, W_mm1, bias_m1,
                                      fc1_w, fc1_b, last_usage, u2,
                                      Abf, WtG, WtS, wbp, Sp, sg2);
    k_gemm2<<<128, 256, 0, stream>>>(Abf, WtG, WtS, wbp, Sp);
    k_final<<<BB, 256, 0, stream>>>(sg2, mem, wbp, Sp, h0, bias, bias_1, bias_2, bias_3, out);
}

// Round 7
// 598.840 us; speedup vs baseline: 1.2748x; 1.2748x over previous
//
#include <hip/hip_runtime.h>

#define BB 256
#define HH 1024
#define MM 256
#define HS 128
#define NH 129  // HS+1

typedef __attribute__((ext_vector_type(8))) short short8;
typedef __attribute__((ext_vector_type(4))) float float4v;

__device__ __forceinline__ float sigmoidf_(float x) { return 1.0f / (1.0f + expf(-x)); }
__device__ __forceinline__ float gumbelf_(float u) { return -logf(1e-20f - logf(1e-20f + u)); }

__device__ __forceinline__ unsigned short f2bf(float x) {
    union { float f; unsigned u; } c; c.f = x;
    unsigned u = c.u;
    return (unsigned short)((u + 0x7FFFu + ((u >> 16) & 1u)) >> 16);
}

// ---------------------------------------------------------------- L1: score1 (bx<256, 16 waves) + weight cvt (bx>=256, 4 tiles/block)
__global__ __launch_bounds__(1024) void k_score1cvt(const float* __restrict__ input_,
                                                    const float* __restrict__ h0,
                                                    const float* __restrict__ W_im,
                                                    const float* __restrict__ W_hm,
                                                    const float* __restrict__ fc1_w,
                                                    const float* __restrict__ fc1_b,
                                                    const float* __restrict__ mem,
                                                    const float* __restrict__ last_usage,
                                                    const float* __restrict__ u1,
                                                    const float* __restrict__ W_ih,
                                                    const float* __restrict__ W_hh,
                                                    const float* __restrict__ W_rh,
                                                    const float* __restrict__ W_s1,
                                                    const float* __restrict__ W_s2,
                                                    const float* __restrict__ W_s3,
                                                    unsigned short* __restrict__ Abf,
                                                    unsigned short* __restrict__ WtG,
                                                    unsigned short* __restrict__ WtS,
                                                    float* __restrict__ sg_out) {
    __shared__ __align__(16) unsigned char smem[33792];
    int bx = blockIdx.x, t = threadIdx.x;
    if (bx >= 256) {
        // ---- weight convert/transpose: 4 tiles per block, one per 256-thread subgroup
        int sub = t >> 8, tloc = t & 255;
        unsigned short (*T)[66] = (unsigned short (*)[66])(smem + sub * 8448);
        int tile = (bx - 256) * 4 + sub;   // 0..3071
        const float* src;
        unsigned short* dst;
        int k0, n0, sstr, dstr, krel;
        if (tile < 2304) {
            int kt = tile / 48, nt = tile % 48;
            k0 = kt * 64; n0 = nt * 64;
            src = (k0 < 1024) ? W_ih : (k0 < 2048) ? W_hh : W_rh;
            krel = k0 & 1023;
            dst = WtG; sstr = 3072; dstr = 3072;
        } else {
            int r = tile - 2304;
            int seg = r >> 8;
            int rem = r & 255;
            int kt = rem >> 4, nt = rem & 15;
            k0 = kt * 64; n0 = nt * 64;
            src = (seg == 0) ? W_s1 : (seg == 1) ? W_s2 : W_s3;
            krel = k0;
            dst = WtS + (size_t)seg * 1048576; sstr = 1024; dstr = 1024;
        }
        for (int i = 0; i < 4; ++i) {
            int e = i * 256 + tloc;
            int kk = e >> 4, nn0 = (e & 15) * 4;
            float4 v = *(const float4*)(src + (size_t)(krel + kk) * sstr + n0 + nn0);
            T[nn0 + 0][kk] = f2bf(v.x);
            T[nn0 + 1][kk] = f2bf(v.y);
            T[nn0 + 2][kk] = f2bf(v.z);
            T[nn0 + 3][kk] = f2bf(v.w);
        }
        __syncthreads();
        for (int i = 0; i < 8; ++i) {
            int e = i * 256 + tloc;
            int nn = e >> 5, kk2 = (e & 31) * 2;
            unsigned val = (unsigned)T[nn][kk2] | ((unsigned)T[nn][kk2 + 1] << 16);
            *(unsigned*)(dst + (size_t)(n0 + nn) * dstr + k0 + kk2) = val;
        }
        return;
    }
    // ---- score pass 1 (identical structure to round-5 k_score1: 1024 threads, 16 waves)
    float* sx = (float*)smem;              // 1024
    float* sh = sx + 1024;                 // 1024
    float* sv = sh + 1024;                 // 1024
    float* red = sv + 1024;                // 8*128
    float* red2 = red + 1024;              // 8
    float* sj = red2 + 8;                  // 129
    float* scb = sj + 129;                 // 1
    int b = bx;
    if (t < 256) {
        float4 v = *(const float4*)(input_ + (size_t)b * HH + t * 4);
        *(float4*)(sx + t * 4) = v;
        ushort4 o; o.x = f2bf(v.x); o.y = f2bf(v.y); o.z = f2bf(v.z); o.w = f2bf(v.w);
        *(ushort4*)(Abf + (size_t)b * 3072 + t * 4) = o;
    } else if (t < 512) {
        int tt = t - 256;
        float4 v = *(const float4*)(h0 + (size_t)b * HH + tt * 4);
        *(float4*)(sh + tt * 4) = v;
        ushort4 o; o.x = f2bf(v.x); o.y = f2bf(v.y); o.z = f2bf(v.z); o.w = f2bf(v.w);
        *(ushort4*)(Abf + (size_t)b * 3072 + 1024 + tt * 4) = o;
    }
    __syncthreads();
    {   // read_head GEMV: j = t&127, 8-way K-split
        int j = t & 127, ks = t >> 7;
        int hb = ks * 128;
        float p = 0.f;
#pragma unroll 8
        for (int h = hb; h < hb + 128; ++h)
            p += sx[h] * W_im[h * NH + j] + sh[h] * W_hm[h * NH + j];
        red[ks * 128 + j] = p;
        if (t >= 1016) {  // j = 128 extra slices
            int k2 = t - 1016;
            int hb2 = k2 * 128;
            float q = 0.f;
#pragma unroll 8
            for (int h = hb2; h < hb2 + 128; ++h)
                q += sx[h] * W_im[h * NH + 128] + sh[h] * W_hm[h * NH + 128];
            red2[k2] = q;
        }
    }
    __syncthreads();
    if (t < 128) {
        float s = 0.f;
        for (int k = 0; k < 8; ++k) s += red[k * 128 + t];
        sj[t] = tanhf(s);
    } else if (t == 128) {
        float s = 0.f;
        for (int k = 0; k < 8; ++k) s += red2[k];
        sj[128] = tanhf(s);
    }
    __syncthreads();
    {   // v projection
        float acc = 0.f;
#pragma unroll 4
        for (int j = 0; j < HS; ++j) acc += sj[j] * fc1_w[(size_t)j * HH + t];
        sv[t] = acc;
    }
    if (t < 64) {
        float p = sj[t] * fc1_b[t] + sj[t + 64] * fc1_b[t + 64];
        for (int off = 32; off > 0; off >>= 1) p += __shfl_down(p, off, 64);
        if (t == 0) *scb = p;
    }
    __syncthreads();
    float cb = *scb, hf = sj[128];
    int wave = t >> 6, lane = t & 63;
    float4 rv[4];
#pragma unroll
    for (int it = 0; it < 4; ++it) rv[it] = *(const float4*)(sv + it * 256 + lane * 4);
    for (int i = 0; i < 16; ++i) {
        int m = wave * 16 + i;
        const float* row = (m == 0) ? (h0 + (size_t)b * HH) : (mem + ((size_t)(b * MM + m)) * HH);
        float p = 0.f;
#pragma unroll
        for (int it = 0; it < 4; ++it) {
            float4 mv = *(const float4*)(row + it * 256 + lane * 4);
            p += mv.x * rv[it].x + mv.y * rv[it].y + mv.z * rv[it].z + mv.w * rv[it].w;
        }
        for (int off = 32; off > 0; off >>= 1) p += __shfl_down(p, off, 64);
        if (lane == 0) {
            float lu = sigmoidf_(last_usage[b * MM + m]);
            sg_out[b * MM + m] = p + cb + hf * lu + gumbelf_(u1[b * MM + m]);
        }
    }
}

// ---------------------------------------------------------------- L2: sel1+head1+scores pass 2 (round-5 verbatim)
__global__ __launch_bounds__(1024) void k_sel_score2(const float* __restrict__ sg1,
                                                     const float* __restrict__ mem,
                                                     const float* __restrict__ h0,
                                                     const float* __restrict__ input_,
                                                     const float* __restrict__ W_im1,
                                                     const float* __restrict__ W_hm1,
                                                     const float* __restrict__ W_mm1,
                                                     const float* __restrict__ bias_m1,
                                                     const float* __restrict__ fc1_w,
                                                     const float* __restrict__ fc1_b,
                                                     const float* __restrict__ last_usage,
                                                     const float* __restrict__ u2,
                                                     unsigned short* __restrict__ Abf,
                                                     float* __restrict__ sg_out) {
    __shared__ float svals[256];
    __shared__ int sidx[256];
    __shared__ float sx[HH], sh[HH], se[HH], sv[HH];
    __shared__ float red[8][128];
    __shared__ float red2[8];
    __shared__ float sj[NH];
    __shared__ float scb;
    int b = blockIdx.x, t = threadIdx.x;
    if (t < 256) {
        svals[t] = sg1[b * MM + t];
        sidx[t] = t;
    }
    __syncthreads();
    for (int s = 128; s > 0; s >>= 1) {
        if (t < s) {
            if (svals[t + s] > svals[t]) { svals[t] = svals[t + s]; sidx[t] = sidx[t + s]; }
        }
        __syncthreads();
    }
    int mstar = sidx[0];
    const float* erow = (mstar == 0) ? (h0 + (size_t)b * HH) : (mem + ((size_t)(b * MM + mstar)) * HH);
    if (t < 256) {
        float4 v = *(const float4*)(erow + t * 4);
        *(float4*)(se + t * 4) = v;
        ushort4 o; o.x = f2bf(v.x); o.y = f2bf(v.y); o.z = f2bf(v.z); o.w = f2bf(v.w);
        *(ushort4*)(Abf + (size_t)b * 3072 + 2048 + t * 4) = o;
    } else if (t < 512) {
        int tt = t - 256;
        *(float4*)(sx + tt * 4) = *(const float4*)(input_ + (size_t)b * HH + tt * 4);
    } else if (t < 768) {
        int tt = t - 512;
        *(float4*)(sh + tt * 4) = *(const float4*)(h0 + (size_t)b * HH + tt * 4);
    }
    __syncthreads();
    {
        int j = t & 127, ks = t >> 7;
        int hb = ks * 128;
        float p = 0.f;
#pragma unroll 4
        for (int h = hb; h < hb + 128; ++h)
            p += sx[h] * W_im1[h * NH + j] + sh[h] * W_hm1[h * NH + j] + se[h] * W_mm1[h * NH + j];
        red[ks][j] = p;
        if (t >= 1016) {
            int k2 = t - 1016;
            int hb2 = k2 * 128;
            float q = 0.f;
#pragma unroll 4
            for (int h = hb2; h < hb2 + 128; ++h)
                q += sx[h] * W_im1[h * NH + 128] + sh[h] * W_hm1[h * NH + 128] + se[h] * W_mm1[h * NH + 128];
            red2[k2] = q;
        }
    }
    __syncthreads();
    if (t < 128) {
        float s = bias_m1[t];
        for (int k = 0; k < 8; ++k) s += red[k][t];
        sj[t] = tanhf(s);
    } else if (t == 128) {
        float s = bias_m1[128];
        for (int k = 0; k < 8; ++k) s += red2[k];
        sj[128] = tanhf(s);
    }
    __syncthreads();
    {
        float acc = 0.f;
#pragma unroll 4
        for (int j = 0; j < HS; ++j) acc += sj[j] * fc1_w[(size_t)j * HH + t];
        sv[t] = acc;
    }
    if (t < 64) {
        float p = sj[t] * fc1_b[t] + sj[t + 64] * fc1_b[t + 64];
        for (int off = 32; off > 0; off >>= 1) p += __shfl_down(p, off, 64);
        if (t == 0) scb = p;
    }
    __syncthreads();
    float cb = scb, hf = sj[128];
    int wave = t >> 6, lane = t & 63;
    float4 rv[4];
#pragma unroll
    for (int it = 0; it < 4; ++it) rv[it] = *(const float4*)(sv + it * 256 + lane * 4);
    for (int i = 0; i < 16; ++i) {
        int m = wave * 16 + i;
        const float* row = (m == 0) ? (h0 + (size_t)b * HH) : (mem + ((size_t)(b * MM + m)) * HH);
        float p = 0.f;
#pragma unroll
        for (int it = 0; it < 4; ++it) {
            float4 mv = *(const float4*)(row + it * 256 + lane * 4);
            p += mv.x * rv[it].x + mv.y * rv[it].y + mv.z * rv[it].z + mv.w * rv[it].w;
        }
        for (int off = 32; off > 0; off >>= 1) p += __shfl_down(p, off, 64);
        if (lane == 0) {
            float lu = sigmoidf_(last_usage[b * MM + m]);
            sg_out[b * MM + m] = p + cb + hf * lu + gumbelf_(u2[b * MM + m]);
        }
    }
}

// ---------------------------------------------------------------- L3: MFMA GEMM (round-5 verbatim, all 192 units)
__global__ __launch_bounds__(256) void k_gemm(const unsigned short* __restrict__ Abf,
                                              const unsigned short* __restrict__ WtG,
                                              const unsigned short* __restrict__ WtS,
                                              float* __restrict__ wbp,
                                              float* __restrict__ Sp) {
    __shared__ unsigned short As[128 * 72];
    __shared__ unsigned short Bs[128 * 72];
    int bx = blockIdx.x;
    int mtile = bx & 1, unit = bx >> 1;
    int m0 = mtile * 128;
    const unsigned short* Bp;
    const unsigned short* Ap;
    float* pout;
    int bstr, ncol0;
    if (unit < 144) {
        int nt = unit % 24;
        int kidx = unit / 24;          // 0..5
        int ksel = kidx >> 1, khalf = kidx & 1;
        ncol0 = nt * 128;
        Bp = WtG + (size_t)ncol0 * 3072 + ksel * 1024 + khalf * 512;
        bstr = 3072;
        Ap = Abf + ksel * 1024 + khalf * 512;
        pout = wbp + (size_t)kidx * 786432;
    } else {
        int su = unit - 144;           // 0..47
        int seg = su / 16;
        int rem = su % 16;
        int khalf = rem >> 3, nts = rem & 7;
        ncol0 = seg * 1024 + nts * 128;
        Bp = WtS + (size_t)seg * 1048576 + (size_t)(nts * 128) * 1024 + khalf * 512;
        bstr = 1024;
        Ap = Abf + seg * 1024 + khalf * 512;
        pout = Sp + (size_t)khalf * 786432;
    }

    int tid = threadIdx.x;
    int wave = tid >> 6, lane = tid & 63;
    int wm = wave >> 1, wn = wave & 1;
    int q = lane >> 4, lm = lane & 15;

    float4v acc[4][4];
    for (int i = 0; i < 4; ++i)
        for (int j = 0; j < 4; ++j)
            acc[i][j] = (float4v){0.f, 0.f, 0.f, 0.f};

    for (int kt = 0; kt < 512; kt += 64) {
        for (int rr = 0; rr < 4; ++rr) {
            int e = rr * 256 + tid;
            int row = e >> 3, cg = e & 7;
            *(uint4*)&As[row * 72 + cg * 8] =
                *(const uint4*)(Ap + (size_t)(m0 + row) * 3072 + kt + cg * 8);
            *(uint4*)&Bs[row * 72 + cg * 8] =
                *(const uint4*)(Bp + (size_t)row * bstr + kt + cg * 8);
        }
        __syncthreads();
        for (int ks = 0; ks < 64; ks += 32) {
            short8 av[4], bv[4];
            for (int i = 0; i < 4; ++i)
                av[i] = *(const short8*)&As[(wm * 64 + i * 16 + lm) * 72 + ks + q * 8];
            for (int j = 0; j < 4; ++j)
                bv[j] = *(const short8*)&Bs[(wn * 64 + j * 16 + lm) * 72 + ks + q * 8];
            for (int i = 0; i < 4; ++i)
                for (int j = 0; j < 4; ++j)
                    acc[i][j] = __builtin_amdgcn_mfma_f32_16x16x32_bf16(av[i], bv[j], acc[i][j], 0, 0, 0);
        }
        __syncthreads();
    }

    for (int i = 0; i < 4; ++i)
        for (int j = 0; j < 4; ++j) {
            int n = ncol0 + wn * 64 + j * 16 + lm;
            for (int reg = 0; reg < 4; ++reg) {
                int m = m0 + wm * 64 + i * 16 + q * 4 + reg;
                pout[(size_t)m * 3072 + n] = acc[i][j][reg];
            }
        }
}

// ---------------------------------------------------------------- L4: final (round-5 verbatim)
__global__ __launch_bounds__(256) void k_final(const float* __restrict__ sg2,
                                               const float* __restrict__ mem,
                                               const float* __restrict__ wbp,
                                               const float* __restrict__ Sp,
                                               const float* __restrict__ h0,
                                               const float* __restrict__ bias,
                                               const float* __restrict__ b1,
                                               const float* __restrict__ b2,
                                               const float* __restrict__ b3,
                                               float* __restrict__ out) {
    __shared__ float svals[256];
    __shared__ int sidx[256];
    int b = blockIdx.x, t = threadIdx.x;
    svals[t] = sg2[b * MM + t];
    sidx[t] = t;
    __syncthreads();
    for (int s = 128; s > 0; s >>= 1) {
        if (t < s) {
            if (svals[t + s] > svals[t]) { svals[t] = svals[t + s]; sidx[t] = sidx[t + s]; }
        }
        __syncthreads();
    }
    int mstar = sidx[0];
    const float* erow = (mstar == 0) ? (h0 + (size_t)b * HH) : (mem + ((size_t)(b * MM + mstar)) * HH);
    float* o_row = out + (size_t)BB * HH + (size_t)b * 2 * HH;
    {
        int hb = t * 4;
        *(float4*)(o_row + HH + hb) = *(const float4*)(erow + hb);
    }
    int h = t * 4;
    size_t base = (size_t)b * 3072;
    float4 wsum[3];
#pragma unroll
    for (int g = 0; g < 3; ++g) {
        float4 a = make_float4(0.f, 0.f, 0.f, 0.f);
#pragma unroll
        for (int p = 0; p < 6; ++p) {
            float4 w = *(const float4*)(wbp + (size_t)p * 786432 + base + g * 1024 + h);
            a.x += w.x; a.y += w.y; a.z += w.z; a.w += w.w;
        }
        wsum[g] = a;
    }
    float4 bi0 = *(const float4*)(bias + h);
    float4 bi1 = *(const float4*)(bias + 1024 + h);
    float4 bi2 = *(const float4*)(bias + 2048 + h);
    float4 r4 = make_float4(sigmoidf_(wsum[0].x + bi0.x), sigmoidf_(wsum[0].y + bi0.y),
                            sigmoidf_(wsum[0].z + bi0.z), sigmoidf_(wsum[0].w + bi0.w));
    float4 z4 = make_float4(sigmoidf_(wsum[1].x + bi1.x), sigmoidf_(wsum[1].y + bi1.y),
                            sigmoidf_(wsum[1].z + bi1.z), sigmoidf_(wsum[1].w + bi1.w));
    float4 n4 = make_float4(sigmoidf_(wsum[2].x + bi2.x), sigmoidf_(wsum[2].y + bi2.y),
                            sigmoidf_(wsum[2].z + bi2.z), sigmoidf_(wsum[2].w + bi2.w));
    float4 s1, s2, s3;
    {
        float4 a0 = *(const float4*)(Sp + base + h);
        float4 a1 = *(const float4*)(Sp + 786432 + base + h);
        s1 = make_float4(a0.x + a1.x, a0.y + a1.y, a0.z + a1.z, a0.w + a1.w);
        a0 = *(const float4*)(Sp + base + 1024 + h);
        a1 = *(const float4*)(Sp + 786432 + base + 1024 + h);
        s2 = make_float4(a0.x + a1.x, a0.y + a1.y, a0.z + a1.z, a0.w + a1.w);
        a0 = *(const float4*)(Sp + base + 2048 + h);
        a1 = *(const float4*)(Sp + 786432 + base + 2048 + h);
        s3 = make_float4(a0.x + a1.x, a0.y + a1.y, a0.z + a1.z, a0.w + a1.w);
    }
    float4 v1 = *(const float4*)(b1 + h);
    float4 v2 = *(const float4*)(b2 + h);
    float4 v3 = *(const float4*)(b3 + h);
    float4 h0v = *(const float4*)(h0 + (size_t)b * HH + h);
    float4 hn, h1;
    hn.x = tanhf(s1.x + v1.x + r4.x * (s2.x + v2.x) + z4.x * (s3.x + v3.x));
    hn.y = tanhf(s1.y + v1.y + r4.y * (s2.y + v2.y) + z4.y * (s3.y + v3.y));
    hn.z = tanhf(s1.z + v1.z + r4.z * (s2.z + v2.z) + z4.z * (s3.z + v3.z));
    hn.w = tanhf(s1.w + v1.w + r4.w * (s2.w + v2.w) + z4.w * (s3.w + v3.w));
    h1.x = n4.x * hn.x + (1.f - n4.x) * h0v.x;
    h1.y = n4.y * hn.y + (1.f - n4.y) * h0v.y;
    h1.z = n4.z * hn.z + (1.f - n4.z) * h0v.z;
    h1.w = n4.w * hn.w + (1.f - n4.w) * h0v.w;
    *(float4*)(out + (size_t)b * HH + h) = h1;
    *(float4*)(o_row + h) = h1;
}

extern "C" void kernel_launch(void* const* d_in, const int* in_sizes, int n_in,
                              void* d_out, int out_size, void* d_ws, size_t ws_size,
                              hipStream_t stream) {
    const float* input_ = (const float*)d_in[0];
    const float* h0 = (const float*)d_in[1];
    const float* mem = (const float*)d_in[2];
    const float* last_usage = (const float*)d_in[3];
    const float* u1 = (const float*)d_in[4];
    const float* u2 = (const float*)d_in[5];
    const float* W_ih = (const float*)d_in[6];
    const float* W_hh = (const float*)d_in[7];
    const float* W_rh = (const float*)d_in[8];
    const float* W_s1 = (const float*)d_in[9];
    const float* W_s2 = (const float*)d_in[10];
    const float* W_s3 = (const float*)d_in[11];
    const float* bias = (const float*)d_in[12];
    const float* W_im = (const float*)d_in[13];
    const float* W_hm = (const float*)d_in[14];
    const float* fc1_w = (const float*)d_in[15];
    const float* fc1_b = (const float*)d_in[16];
    const float* W_im1 = (const float*)d_in[17];
    const float* W_hm1 = (const float*)d_in[18];
    const float* W_mm1 = (const float*)d_in[19];
    const float* bias_m1 = (const float*)d_in[20];
    const float* bias_1 = (const float*)d_in[21];
    const float* bias_2 = (const float*)d_in[22];
    const float* bias_3 = (const float*)d_in[23];
    float* out = (float*)d_out;

    float* ws = (float*)d_ws;
    float* sg1 = ws;                        // 65536
    float* sg2 = sg1 + 65536;               // 65536
    float* wbp = sg2 + 65536;               // 6 * 786432
    float* Sp = wbp + 6 * 786432;           // 2 * 786432
    unsigned short* Abf = (unsigned short*)(Sp + 2 * 786432);  // 786432 bf16
    unsigned short* WtG = Abf + 786432;     // 9437184 bf16
    unsigned short* WtS = WtG + 9437184;    // 3145728 bf16

    k_score1cvt<<<256 + 768, 1024, 0, stream>>>(input_, h0, W_im, W_hm, fc1_w, fc1_b,
                                                mem, last_usage, u1,
                                                W_ih, W_hh, W_rh, W_s1, W_s2, W_s3,
                                                Abf, WtG, WtS, sg1);
    k_sel_score2<<<BB, 1024, 0, stream>>>(sg1, mem, h0, input_, W_im1, W_hm1, W_mm1, bias_m1,
                                          fc1_w, fc1_b, last_usage, u2, Abf, sg2);
    k_gemm<<<384, 256, 0, stream>>>(Abf, WtG, WtS, wbp, Sp);
    k_final<<<BB, 256, 0, stream>>>(sg2, mem, wbp, Sp, h0, bias, bias_1, bias_2, bias_3, out);
}